// Round 17
// baseline (154.534 us; speedup 1.0000x reference)
//
#include <hip/hip_runtime.h>
#include <hip/hip_fp16.h>

static constexpr int Hh = 384;
static constexpr int Ww = 1280;
static constexpr int HW = Hh * Ww;            // 491520
static constexpr int NPIX = 2 * HW;
static constexpr int TILE_I = 48;             // output tile rows
static constexpr int TILE_J = 40;             // output tile cols
static constexpr int S_STEPS = 8;             // steps per launch; 24 = 3 x 8
static constexpr int RI = TILE_I + 2 * S_STEPS;   // 64
static constexpr int RJ = TILE_J + 2 * S_STEPS;   // 56
static constexpr int RR = RI * RJ;            // 3584
static constexpr int NPAIR_ROW = (RJ - 2) / 2;    // 27 pairs per row
static constexpr int BLOCK = 512;             // 8 waves
static constexpr int PPQ = RR / BLOCK;        // 7 region px / thread (exact)
static constexpr int PPA = 5;                 // pairs/lane (max 10 rows x 27 / 64)
static constexpr int TI_T = Hh / TILE_I;      // 8
static constexpr int TJ_T = Ww / TILE_J;      // 32
static constexpr int GRID = 2 * TI_T * TJ_T;  // 512 = exactly 2 blocks/CU
static constexpr int NXCD = 8;
static constexpr int CHUNK = GRID / NXCD;     // 64 (512 % 8 == 0 -> bijective)
static constexpr float EPSF = 1e-9f;

// k order matches reference PADS: (di,dj) =
// k:   0       1       2       3       4       5       6       7
//    (+1,+1) (+1,0) (+1,-1) (0,+1) (0,-1) (-1,+1) (-1,0) (-1,-1)
__device__ __constant__ int DI_c[8] = { 1, 1, 1, 0, 0, -1, -1, -1 };
__device__ __constant__ int DJ_c[8] = { 1, 0, -1, 1, -1, 1, 0, -1 };

static __device__ __forceinline__ int iclamp(int v, int lo, int hi) {
    return min(max(v, lo), hi);
}

// Precompute per pixel: w'_k (fp16, zeroed where sparse-clamped) and
// C = m ? raw : (1-gate_sum)*raw. (r14-proven; one launch, ~10us.)
__global__ void affinity_norm(const float* __restrict__ g,
                              const float* __restrict__ raw,
                              const float* __restrict__ sparse,
                              __half* __restrict__ wbuf,
                              float* __restrict__ cbuf) {
    int idx = blockIdx.x * blockDim.x + threadIdx.x;
    if (idx >= NPIX) return;
    int b = idx / HW;
    int r = idx - b * HW;
    int i = r / Ww;
    int j = r - i * Ww;

    const float* gb = g + (size_t)b * 8 * HW;
    float v[8];
    float a = EPSF;
#pragma unroll
    for (int k = 0; k < 8; k++) {
        int ii = i + DI_c[k], jj = j + DJ_c[k];
        float gv = 0.0f;
        if (ii >= 0 && ii < Hh && jj >= 0 && jj < Ww)
            gv = gb[k * HW + ii * Ww + jj];
        v[k] = gv;
        a += fabsf(gv);
    }
    float inv = 1.0f / a, gs = 0.0f;
#pragma unroll
    for (int k = 0; k < 8; k++) { v[k] *= inv; gs += v[k]; }

    float rawv = raw[idx];
    bool m = sparse[idx] > 0.0f;   // sparse >= 0 always; sign(s)==1 iff s>0
    cbuf[idx] = m ? rawv : (1.0f - gs) * rawv;
    __half wv[8];
#pragma unroll
    for (int k = 0; k < 8; k++) wv[k] = __float2half(m ? 0.0f : v[k]);
    *(float4*)(wbuf + (size_t)idx * 8) = *(const float4*)wv;
}

// Round-17: r14's geometry (3x8, tile 48x40, 2 blocks/CU, precomputed w/C)
// with the 8 barrier-phases restructured into 4 WAVE-PRIVATE 2-step groups.
//
// Why (r13/r16 evidence): extra co-resident blocks (24 and 32 waves/CU)
// did NOT close the ~15us step-phase gap -> the cost is per-block serial
// barrier convoying, not wave starvation. This kernel halves the barrier
// count: per group, each wave computes step A over its 8-row band +1 halo
// row each side (halo rows duplicated by neighbor waves -- identical
// values, benign write race), then step B on its own band reading ONLY its
// own step-A writes (in-wave LDS ordering + __threadfence_block(); no
// barrier between A and B). One __syncthreads() per group. 3 LDS buffers
// (43KB x 2 blocks = 86KB <= 160): X=step-2g (read-only in group), b1 =
// wave-private scratch (step 2g+1), Z = step 2g+2; X/Z ping-pong across
// groups, b1 reused (only read within its own group, barrier-separated).
// Cost: A-ranges are 10 rows vs 8 owned -> +12.5% px-steps.
//
//  - Shrinking active set, pair-granular (r8-proven): A computes pairs
//    with mring >= sA; B pairs with in-band && mring >= sB. A B-px at
//    ring r reads neighbors ring >= r-1 >= sA -- all A-computed; stale /
//    uninitialized b1 entries are never read.
//  - fp16-packed weights + v_fma_mix inner body (r8/r12/r16-proven,
//    absmax 1.0): persistent = wp 40 + Cc 10 + pr 5 = 55 regs under the
//    (512,2) 128-VGPR budget (knob ledger r3-r6).
//  - Pairs at odd region col -> all +-RJ+-1 tap bases 8B aligned.
//  - blur/din NOT __restrict__ (r11 aliasing fix); launch 1 FIRST=true.
template <bool FIRST>
__global__ __launch_bounds__(BLOCK, 2)
void mega(
    const __half* __restrict__ wbuf,
    const float* __restrict__ cbuf,
    const float* blur,
    const float* din,
    float* __restrict__ dout)
{
    __shared__ float b0[RR], b1[RR], b2[RR];

    const int tid  = threadIdx.x;
    const int wave = tid >> 6;
    const int lane = tid & 63;

    // XCD-aware bijective swizzle (512 = 8*64).
    int bx = ((int)blockIdx.x % NXCD) * CHUNK + (int)blockIdx.x / NXCD;
    const int tj = bx % TJ_T; bx /= TJ_T;
    const int ti = bx % TI_T;
    const int b  = bx / TI_T;
    const int oi = ti * TILE_I - S_STEPS;  // region origin (image coords)
    const int oj = tj * TILE_J - S_STEPS;

    const float* dinb = (FIRST ? blur : din) + (size_t)b * HW;

    // --- stage d0 into b0 (image-clamped; 7x512 exact) ---
#pragma unroll
    for (int q = 0; q < PPQ; q++) {
        int p = tid + q * BLOCK;
        int ri = p / RJ, rj = p - ri * RJ;
        int gi = iclamp(oi + ri, 0, Hh - 1);
        int gj = iclamp(oj + rj, 0, Ww - 1);
        b0[p] = dinb[gi * Ww + gj];
    }

    // --- wave-local pair list over the wave's A-range rows.
    // Wave w owns rows [8w, 8w+8); A-range = owned +-1 halo row, clipped
    // to computable rows [1, 63). pr = p | mring<<16 | inband<<27. ---
    const int rs = (wave == 0) ? 1 : 8 * wave - 1;
    const int re = min(63, 8 * wave + 9);
    const int npairs = (re - rs) * NPAIR_ROW;

    __half2 wp[PPA][8];
    float2  Cc[PPA];
    int     pr[PPA];
#pragma unroll
    for (int q = 0; q < PPA; q++) {
        int m = lane + 64 * q;
        if (m < npairs) {
            int r0 = m / NPAIR_ROW;
            int c0 = m - r0 * NPAIR_ROW;
            int ri = rs + r0;
            int rj = 1 + 2 * c0;           // odd -> aligned b64 tap bases
            int p  = ri * RJ + rj;
            int rngr = min(ri, RI - 1 - ri);
            int rng0 = min(rngr, min(rj,     RJ - 1 - rj));
            int rng1 = min(rngr, min(rj + 1, RJ - 2 - rj));
            int inb  = ((ri >> 3) == wave) ? 1 : 0;
            pr[q] = p | (max(rng0, rng1) << 16) | (inb << 27);
            int gi  = iclamp(oi + ri, 0, Hh - 1);
            int gj0 = iclamp(oj + rj,     0, Ww - 1);
            int gj1 = iclamp(oj + rj + 1, 0, Ww - 1);
            int idx0 = b * HW + gi * Ww + gj0;
            int idx1 = b * HW + gi * Ww + gj1;
            float4 wA = *(const float4*)(wbuf + (size_t)idx0 * 8);
            float4 wB = *(const float4*)(wbuf + (size_t)idx1 * 8);
            const __half* ha = (const __half*)&wA;
            const __half* hb = (const __half*)&wB;
#pragma unroll
            for (int k = 0; k < 8; k++)
                wp[q][k] = __halves2half2(ha[k], hb[k]);
            Cc[q] = make_float2(cbuf[idx0], cbuf[idx1]);
        } else {
            pr[q] = 0;                      // mring 0, not in band
            Cc[q] = make_float2(0.0f, 0.0f);
#pragma unroll
            for (int k = 0; k < 8; k++)
                wp[q][k] = __halves2half2(__float2half(0.0f), __float2half(0.0f));
        }
    }
    __syncthreads();

#define PAIR_BODY(SRC, P, Q)                                           \
    float2 uA = *(const float2*)((SRC) + (P) - RJ - 1);                \
    float2 uB = *(const float2*)((SRC) + (P) - RJ + 1);                \
    float2 mA = *(const float2*)((SRC) + (P) - 1);                     \
    float2 mB = *(const float2*)((SRC) + (P) + 1);                     \
    float2 dA = *(const float2*)((SRC) + (P) + RJ - 1);                \
    float2 dB = *(const float2*)((SRC) + (P) + RJ + 1);                \
    float ax = Cc[Q].x, ay = Cc[Q].y;                                  \
    ax = fmaf(__low2float (wp[Q][0]), dB.x, ax);                       \
    ay = fmaf(__high2float(wp[Q][0]), dB.y, ay);                       \
    ax = fmaf(__low2float (wp[Q][1]), dA.y, ax);                       \
    ay = fmaf(__high2float(wp[Q][1]), dB.x, ay);                       \
    ax = fmaf(__low2float (wp[Q][2]), dA.x, ax);                       \
    ay = fmaf(__high2float(wp[Q][2]), dA.y, ay);                       \
    ax = fmaf(__low2float (wp[Q][3]), mB.x, ax);                       \
    ay = fmaf(__high2float(wp[Q][3]), mB.y, ay);                       \
    ax = fmaf(__low2float (wp[Q][4]), mA.x, ax);                       \
    ay = fmaf(__high2float(wp[Q][4]), mA.y, ay);                       \
    ax = fmaf(__low2float (wp[Q][5]), uB.x, ax);                       \
    ay = fmaf(__high2float(wp[Q][5]), uB.y, ay);                       \
    ax = fmaf(__low2float (wp[Q][6]), uA.y, ax);                       \
    ay = fmaf(__high2float(wp[Q][6]), uB.x, ay);                       \
    ax = fmaf(__low2float (wp[Q][7]), uA.x, ax);                       \
    ay = fmaf(__high2float(wp[Q][7]), uA.y, ay);

    // --- 4 groups of 2 steps; 1 barrier per group boundary ---
#pragma unroll 1
    for (int g = 0; g < 4; ++g) {
        const float* X = (g & 1) ? b2 : b0;
        float* Z = (g & 1) ? b0 : b2;
        const int sA = 2 * g + 1;

        // step A (sA): all pairs with mring >= sA, over the A-range.
#pragma unroll
        for (int q = 0; q < PPA; q++) {
            if (((pr[q] >> 16) & 0xff) >= sA) {
                int p = pr[q] & 0xffff;
                PAIR_BODY(X, p, q);
                b1[p] = ax; b1[p + 1] = ay;
            }
        }
        __threadfence_block();   // order own A-writes before own B-reads

        // step B (sA+1): in-band pairs with mring >= sA+1; reads only
        // rows this wave wrote in A.
        if (g < 3) {
#pragma unroll
            for (int q = 0; q < PPA; q++) {
                if ((pr[q] & (1 << 27)) && ((pr[q] >> 16) & 0xff) >= sA + 1) {
                    int p = pr[q] & 0xffff;
                    PAIR_BODY(b1, p, q);
                    Z[p] = ax; Z[p + 1] = ay;
                }
            }
            __syncthreads();
        } else {
            // final step (8): write centers straight to global.
#pragma unroll
            for (int q = 0; q < PPA; q++) {
                if ((pr[q] & (1 << 27)) && ((pr[q] >> 16) & 0xff) >= S_STEPS) {
                    int p = pr[q] & 0xffff;
                    PAIR_BODY(b1, p, q);
                    int ri = p / RJ, rj = p - ri * RJ;
                    int gbase = b * HW + (oi + ri) * Ww + (oj + rj);
                    if (rj >= S_STEPS && rj < RJ - S_STEPS)
                        dout[gbase]     = ax;
                    if (rj + 1 >= S_STEPS && rj + 1 < RJ - S_STEPS)
                        dout[gbase + 1] = ay;
                }
            }
        }
    }
#undef PAIR_BODY
}

extern "C" void kernel_launch(void* const* d_in, const int* in_sizes, int n_in,
                              void* d_out, int out_size, void* d_ws, size_t ws_size,
                              hipStream_t stream) {
    const float* guidance = (const float*)d_in[0];
    const float* blur     = (const float*)d_in[1];
    const float* sparse   = (const float*)d_in[2];
    float* out = (float*)d_out;

    char* ws = (char*)d_ws;
    float* bufA = (float*)ws;
    float* bufB = bufA + NPIX;
    __half* wbuf = (__half*)(bufB + NPIX);          // NPIX*8 fp16 = 15.7 MB
    float*  cbuf = (float*)(wbuf + (size_t)NPIX * 8);

    const int threads = 256;
    const int blocks = (NPIX + threads - 1) / threads;
    affinity_norm<<<blocks, threads, 0, stream>>>(guidance, blur, sparse, wbuf, cbuf);

    // 24 steps = 3 launches x 8 fused steps
    mega<true ><<<GRID, BLOCK, 0, stream>>>(wbuf, cbuf, blur, nullptr, bufA);
    mega<false><<<GRID, BLOCK, 0, stream>>>(wbuf, cbuf, nullptr, bufA, bufB);
    mega<false><<<GRID, BLOCK, 0, stream>>>(wbuf, cbuf, nullptr, bufB, out);
}